// Round 4
// baseline (524.540 us; speedup 1.0000x reference)
//
#include <hip/hip_runtime.h>

#define N_NODES 100000
#define N_EDGES 400000
#define HALF_E  200000
#define BN_EPS  1e-5f

// A_bf layout per node row: [in 200 | out 200 | x 200 | pad 40] = 640 bf16 (1280 B)
// Within each 32-bf16 (64 B) chunk, 16B slot s of row v is stored at physical
// slot s ^ ((v>>1)&3)  -> linear global_load_lds staging + XOR'd ds_read_b128
// gives conflict-free (2-way) LDS reads in the GEMM (rule 21: source-side
// pre-swizzle + same XOR on read).
#define KTOT   640
#define CHUNKS 20
#define GEMM_NBLK 782

// LDS tile per buffer: A [0, 8192) = 128 rows x 64 B, W [8192, 24576) = 16 rows x 1024 B
// (W rows 13-15 staged with in-bounds garbage for uniform 6 loads/wave; never read)
#define LDS_BUF_BYTES 24576
#define LDS_W_OFF     8192

#define XSEG_NBLK 25000
#define PACK_NBLK 520
#define HIST_NBLK 1563
#define PREP_NBLK (XSEG_NBLK + PACK_NBLK + HIST_NBLK)

typedef __bf16 bf16x8 __attribute__((ext_vector_type(8)));
typedef float  f32x4  __attribute__((ext_vector_type(4)));

// ---- workspace layout (bytes) ----
#define A_OFF      0ull                  // 100000*640*2 = 128,000,000
#define WT_OFF     128000000ull          // 20*208*64 B = 266,240 (chunk-major, pre-swizzled)
#define HIST_OFF   128266240ull          // 100000*4
#define CURSOR_OFF 128666240ull          // 100000*4
#define ZERO_BASE  HIST_OFF
#define ZERO_BYTES 800000ull             // hist+cursor
#define SCALE_OFF  129066240ull          // 200*4
#define SHIFT_OFF  129067040ull          // 200*4
#define ROWPTR_OFF 129069440ull          // 100001*4
#define REC_OFF    129470640ull          // 400000*16 = 6,400,000 (16B aligned)
#define PS_OFF     135870640ull          // 782*200*4 = 625,600
#define PQ_OFF     136496240ull          // 782*200*4 -> end 137,121,840

static __device__ __forceinline__ unsigned short f2bf(float f) {
    union { float f; unsigned u; } v; v.f = f;
    unsigned u = v.u;
    unsigned r = (u + 0x7fffu + ((u >> 16) & 1u)) >> 16;  // RNE
    return (unsigned short)r;
}
static __device__ __forceinline__ float bf2f(unsigned short s) {
    union { unsigned u; float f; } v; v.u = ((unsigned)s) << 16; return v.f;
}

// physical bf16 offset of logical k within a row, given row swizzle s = (v>>1)&3
static __device__ __forceinline__ int swzk(int k, int s) {
    return (k & ~31) | (k & 7) | ((((k >> 3) & 3) ^ s) << 3);
}

// async global->LDS, 16 B per lane, linear LDS dest (wave-uniform base + lane*16)
static __device__ __forceinline__ void gload16(const void* g, void* l) {
    __builtin_amdgcn_global_load_lds(
        (const __attribute__((address_space(1))) void*)g,
        (__attribute__((address_space(3))) void*)l, 16, 0, 0);
}

// ---- fused prep: [0,25000) swizzled x-segment of A + zero pad;
// ---- [25000,25520) pack Wt; [25520,27083) dst-histogram (hist pre-zeroed by memset) ----
__global__ __launch_bounds__(256) void prep_k(
    const float* __restrict__ x,
    const float* __restrict__ in_w, const float* __restrict__ out_w,
    const float* __restrict__ loop_w, const float* __restrict__ loop_rel,
    const int* __restrict__ edst,
    unsigned short* __restrict__ A, unsigned short* __restrict__ Wt,
    unsigned* __restrict__ hist) {
    int b = blockIdx.x;
    if (b < XSEG_NBLK) {
        int v = b * 4 + (threadIdx.x >> 6);
        int lane = threadIdx.x & 63;
        int s = (v >> 1) & 3;
        unsigned short* ar = A + (size_t)v * KTOT;
        if (lane < 50) {
            float4 xv = *reinterpret_cast<const float4*>(x + v * 200 + lane * 4);
            ushort4 w = make_ushort4(f2bf(xv.x), f2bf(xv.y), f2bf(xv.z), f2bf(xv.w));
            *reinterpret_cast<ushort4*>(ar + swzk(400 + lane * 4, s)) = w;
        }
        if (lane < 10)
            *reinterpret_cast<ushort4*>(ar + swzk(600 + lane * 4, s)) = make_ushort4(0, 0, 0, 0);
    } else if (b < XSEG_NBLK + PACK_NBLK) {
        // Wt layout: [c 20][n 208][slot_phys 4][8 bf16]
        int idx = (b - XSEG_NBLK) * 256 + threadIdx.x;   // 520*256 == 20*208*32
        int e = idx & 7;
        int t = idx >> 3;
        int sp = t & 3;
        int t2 = t >> 2;
        int n = t2 % 208;
        int c = t2 / 208;
        int sl = sp ^ ((n >> 1) & 3);
        int k = c * 32 + sl * 8 + e;
        float v = 0.f;
        if (n < 200) {
            if (k < 200)       v = in_w[k * 200 + n];
            else if (k < 400)  v = out_w[(k - 200) * 200 + n];
            else if (k < 600)  v = loop_w[(k - 400) * 200 + n] * loop_rel[k - 400];
        }
        Wt[idx] = f2bf(v);
    } else {
        int e = (b - XSEG_NBLK - PACK_NBLK) * 256 + threadIdx.x;
        if (e < N_EDGES) atomicAdd(&hist[edst[e]], 1u);
    }
}

// ---- single-block exclusive scan of hist[100000] -> rowptr ----
__global__ __launch_bounds__(1024) void scan_all(const unsigned* __restrict__ hist,
                                                 unsigned* __restrict__ rowptr) {
    __shared__ unsigned ps[1024];
    const int PER = 98;                   // 1024*98 = 100352 >= 100000
    int t = threadIdx.x;
    int base = t * PER;
    unsigned s = 0;
    for (int i = 0; i < PER; ++i) {
        int idx = base + i;
        if (idx < N_NODES) s += hist[idx];
    }
    ps[t] = s;
    __syncthreads();
    for (int off = 1; off < 1024; off <<= 1) {
        unsigned v = 0;
        if (t >= off) v = ps[t - off];
        __syncthreads();
        if (t >= off) ps[t] += v;
        __syncthreads();
    }
    unsigned run = (t == 0) ? 0u : ps[t - 1];
    for (int i = 0; i < PER; ++i) {
        int idx = base + i;
        if (idx < N_NODES) {
            rowptr[idx] = run;
            run += hist[idx];
        }
    }
    if (t == 1023) rowptr[N_NODES] = N_EDGES;
}

// ---- CSR fill: packed edge records {src, type, norm, dir} at sorted positions ----
__global__ __launch_bounds__(256) void fill_k(
    const int* __restrict__ edst, const int* __restrict__ esrc,
    const int* __restrict__ etyp, const float* __restrict__ norm,
    const unsigned* __restrict__ rowptr, unsigned* __restrict__ cursor,
    int4* __restrict__ recs) {
    int e = blockIdx.x * 256 + threadIdx.x;
    if (e < N_EDGES) {
        int d = edst[e];
        unsigned pos = rowptr[d] + atomicAdd(&cursor[d], 1u);
        recs[pos] = make_int4(esrc[e], etyp[e], __float_as_int(norm[e]), (e < HALF_E) ? 1 : 0);
    }
}

// ---- gather aggregation: one wave per dst node; swizzled bf16 x-rows ----
// 4 edges in flight per iteration (8 outstanding VMEM) to cover gather latency.
__global__ __launch_bounds__(256) void aggregate(
    const float* __restrict__ rel, const unsigned* __restrict__ rowptr,
    const int4* __restrict__ recs, unsigned short* __restrict__ A) {
    int v = blockIdx.x * 4 + (threadIdx.x >> 6);
    int lane = threadIdx.x & 63;
    bool act = lane < 50;                    // lane owns dims [lane*4, lane*4+4)
    int col = lane * 4;
    int kx = 400 + col;                      // logical x position
    int kxb = (kx & ~31) | (kx & 7);         // swizzle-invariant part
    int kxs = (kx >> 3) & 3;                 // logical slot
    float4 aI = make_float4(0.f, 0.f, 0.f, 0.f);
    float4 aO = make_float4(0.f, 0.f, 0.f, 0.f);

    const unsigned short* __restrict__ Ab = A;
    auto xload = [&](int src) -> ushort4 {
        int s = (src >> 1) & 3;
        return *reinterpret_cast<const ushort4*>(
            Ab + (size_t)src * KTOT + kxb + ((kxs ^ s) << 3));
    };
    auto accum = [&](const int4& r, const ushort4& xv, const float4& rl) {
        float nz = __int_as_float(r.z);
        float mx = bf2f(xv.x) * rl.x * nz;
        float my = bf2f(xv.y) * rl.y * nz;
        float mz = bf2f(xv.z) * rl.z * nz;
        float mw = bf2f(xv.w) * rl.w * nz;
        if (r.w) { aI.x += mx; aI.y += my; aI.z += mz; aI.w += mw; }
        else     { aO.x += mx; aO.y += my; aO.z += mz; aO.w += mw; }
    };

    int beg = rowptr[v], end = rowptr[v + 1];
    int j = beg;
    for (; j + 3 < end; j += 4) {
        int4 r0 = recs[j];
        int4 r1 = recs[j + 1];
        int4 r2 = recs[j + 2];
        int4 r3 = recs[j + 3];
        if (act) {
            ushort4 x0 = xload(r0.x);
            ushort4 x1 = xload(r1.x);
            ushort4 x2 = xload(r2.x);
            ushort4 x3 = xload(r3.x);
            float4 rl0 = *reinterpret_cast<const float4*>(rel + r0.y * 200 + col);
            float4 rl1 = *reinterpret_cast<const float4*>(rel + r1.y * 200 + col);
            float4 rl2 = *reinterpret_cast<const float4*>(rel + r2.y * 200 + col);
            float4 rl3 = *reinterpret_cast<const float4*>(rel + r3.y * 200 + col);
            accum(r0, x0, rl0);
            accum(r1, x1, rl1);
            accum(r2, x2, rl2);
            accum(r3, x3, rl3);
        }
    }
    if (j + 1 < end) {
        int4 r0 = recs[j];
        int4 r1 = recs[j + 1];
        if (act) {
            ushort4 x0 = xload(r0.x);
            ushort4 x1 = xload(r1.x);
            float4 rl0 = *reinterpret_cast<const float4*>(rel + r0.y * 200 + col);
            float4 rl1 = *reinterpret_cast<const float4*>(rel + r1.y * 200 + col);
            accum(r0, x0, rl0);
            accum(r1, x1, rl1);
        }
        j += 2;
    }
    if (j < end) {
        int4 r0 = recs[j];
        if (act) {
            ushort4 x0 = xload(r0.x);
            float4 rl0 = *reinterpret_cast<const float4*>(rel + r0.y * 200 + col);
            accum(r0, x0, rl0);
        }
    }
    if (act) {
        int sv = (v >> 1) & 3;
        unsigned short* ar = A + (size_t)v * KTOT;
        ushort4 wI = make_ushort4(f2bf(aI.x), f2bf(aI.y), f2bf(aI.z), f2bf(aI.w));
        ushort4 wO = make_ushort4(f2bf(aO.x), f2bf(aO.y), f2bf(aO.z), f2bf(aO.w));
        *reinterpret_cast<ushort4*>(ar + swzk(col, sv))       = wI;
        *reinterpret_cast<ushort4*>(ar + swzk(200 + col, sv)) = wO;
    }
}

// ---- GEMM: out[v][n] = A_bf[v][:] . Wt[n][:] / 3 ; per-block BN partials ----
// Counted-vmcnt pipeline (guide T4): stage 2 chunks ahead (12 loads in flight),
// raw s_barrier + s_waitcnt vmcnt(6) per chunk -> next chunk's prefetch is
// NEVER drained by a barrier. Uniform 6 loads/wave/chunk (2 A + 4 W; W rows
// 13-15 are in-bounds garbage, never read by MFMA).
__global__ __launch_bounds__(256) void gemm_nodes(
    const unsigned short* __restrict__ A, const unsigned short* __restrict__ Wt,
    float* __restrict__ out, float* __restrict__ PS, float* __restrict__ PQ) {
    __shared__ __align__(16) char lds[2][LDS_BUF_BYTES];
    int tid = threadIdx.x;
    int wave = tid >> 6, lane = tid & 63;
    int quad = lane >> 4, l15 = lane & 15;
    int row0 = blockIdx.x * 128;
    int pslot16 = ((quad ^ ((l15 >> 1) & 3)) << 4);   // physical 16B slot for reads

    // staging sources: wave stages A rows [(wave*2+p)*16, +16), lane -> (row lane>>2, slot lane&3)
    int sv0 = row0 + (wave * 2 + 0) * 16 + (lane >> 2);
    int sv1 = row0 + (wave * 2 + 1) * 16 + (lane >> 2);
    if (sv0 >= N_NODES) sv0 = N_NODES - 1;   // clamp; excluded from out/stats below
    if (sv1 >= N_NODES) sv1 = N_NODES - 1;
    const char* Ab = (const char*)A;
    const char* srcA0 = Ab + (size_t)sv0 * 1280 + (lane & 3) * 16;
    const char* srcA1 = Ab + (size_t)sv1 * 1280 + (lane & 3) * 16;
    const char* Wb = (const char*)Wt + lane * 16;

    // LDS read offsets
    int rdA0 = ((wave * 2 + 0) * 16 + l15) * 64 + pslot16;
    int rdA1 = ((wave * 2 + 1) * 16 + l15) * 64 + pslot16;
    int rdB  = LDS_W_OFF + l15 * 64 + pslot16;

    f32x4 acc[2][13];
#pragma unroll
    for (int i = 0; i < 2; ++i)
#pragma unroll
        for (int j = 0; j < 13; ++j) {
            acc[i][j].x = 0.f; acc[i][j].y = 0.f; acc[i][j].z = 0.f; acc[i][j].w = 0.f;
        }

    // stage chunk c into buffer lb: exactly 6 loads per wave
    auto stage = [&](int c, char* lb) {
        gload16(srcA0 + c * 64, lb + (wave * 2 + 0) * 1024);
        gload16(srcA1 + c * 64, lb + (wave * 2 + 1) * 1024);
        const char* wsrc = Wb + (size_t)c * 13312;
#pragma unroll
        for (int i = 0; i < 4; ++i) {
            int r = wave + i * 4;                 // LDS W row 0..15
            int srcr = (r < 13) ? r : (r - 13);   // in-bounds garbage for 13..15
            gload16(wsrc + srcr * 1024, lb + LDS_W_OFF + r * 1024);
        }
    };

    stage(0, lds[0]);
    stage(1, lds[1]);

#pragma unroll
    for (int c = 0; c < CHUNKS; ++c) {
        char* lb = lds[c & 1];
        if (c < CHUNKS - 1) {
            asm volatile("s_waitcnt vmcnt(6)" ::: "memory");   // chunk c's 6 done
        } else {
            asm volatile("s_waitcnt vmcnt(0)" ::: "memory");
        }
        __builtin_amdgcn_sched_barrier(0);
        __builtin_amdgcn_s_barrier();       // all waves' chunk-c data in LDS
        __builtin_amdgcn_sched_barrier(0);
        bf16x8 a0 = *reinterpret_cast<const bf16x8*>(lb + rdA0);
        bf16x8 a1 = *reinterpret_cast<const bf16x8*>(lb + rdA1);
#pragma unroll
        for (int nt = 0; nt < 13; ++nt) {
            bf16x8 b = *reinterpret_cast<const bf16x8*>(lb + rdB + nt * 1024);
            acc[0][nt] = __builtin_amdgcn_mfma_f32_16x16x32_bf16(a0, b, acc[0][nt], 0, 0, 0);
            acc[1][nt] = __builtin_amdgcn_mfma_f32_16x16x32_bf16(a1, b, acc[1][nt], 0, 0, 0);
        }
        __builtin_amdgcn_s_barrier();       // all waves done reading lb
        __builtin_amdgcn_sched_barrier(0);
        if (c + 2 < CHUNKS) stage(c + 2, lb);
    }

    // epilogue: store /3; per-wave column stats -> LDS -> per-block partials
    float* redS = reinterpret_cast<float*>(lds[0]);        // [4][200]
    float* redQ = reinterpret_cast<float*>(lds[0]) + 800;  // [4][200]
#pragma unroll
    for (int nt = 0; nt < 13; ++nt) {
        int n = nt * 16 + l15;
        float s = 0.f, q = 0.f;
#pragma unroll
        for (int i = 0; i < 2; ++i) {
            int mbase = row0 + (wave * 2 + i) * 16 + quad * 4;
#pragma unroll
            for (int r = 0; r < 4; ++r) {
                float val = acc[i][nt][r] * (1.f / 3.f);
                int m = mbase + r;
                if (m < N_NODES) {
                    if (n < 200) out[m * 200 + n] = val;
                    s += val; q += val * val;
                }
            }
        }
        s += __shfl_xor(s, 16); s += __shfl_xor(s, 32);
        q += __shfl_xor(q, 16); q += __shfl_xor(q, 32);
        if (lane < 16 && n < 200) {
            redS[wave * 200 + n] = s;
            redQ[wave * 200 + n] = q;
        }
    }
    __syncthreads();
    if (tid < 200) {
        float s = redS[tid] + redS[200 + tid] + redS[400 + tid] + redS[600 + tid];
        float q = redQ[tid] + redQ[200 + tid] + redQ[400 + tid] + redQ[600 + tid];
        PS[blockIdx.x * 200 + tid] = s;
        PQ[blockIdx.x * 200 + tid] = q;
    }
}

// ---- fused: blocks [0,200) BN-reduce per column; blocks [200,400) rel_out rows ----
__global__ __launch_bounds__(256) void bnred_rel(
    const float* __restrict__ PS, const float* __restrict__ PQ,
    const float* __restrict__ gamma, const float* __restrict__ beta,
    const float* __restrict__ rel, const float* __restrict__ w,
    float* __restrict__ scale, float* __restrict__ shift,
    float* __restrict__ rel_out) {
    if (blockIdx.x < 200) {
        __shared__ float ls[256], lq[256];
        int c = blockIdx.x;
        float s = 0.f, q = 0.f;
        for (int b = threadIdx.x; b < GEMM_NBLK; b += 256) {
            s += PS[b * 200 + c];
            q += PQ[b * 200 + c];
        }
        ls[threadIdx.x] = s; lq[threadIdx.x] = q;
        __syncthreads();
        for (int off = 128; off > 0; off >>= 1) {
            if (threadIdx.x < off) {
                ls[threadIdx.x] += ls[threadIdx.x + off];
                lq[threadIdx.x] += lq[threadIdx.x + off];
            }
            __syncthreads();
        }
        if (threadIdx.x == 0) {
            float mean = ls[0] * (1.f / N_NODES);
            float var = lq[0] * (1.f / N_NODES) - mean * mean;
            float inv = rsqrtf(var + BN_EPS);
            float sc = inv * gamma[c];
            scale[c] = sc;
            shift[c] = beta[c] - mean * sc;
        }
    } else {
        int i = blockIdx.x - 200, j = threadIdx.x;
        if (j < 200) {
            float acc = 0.f;
            for (int k = 0; k < 200; ++k) acc += rel[i * 200 + k] * w[k * 200 + j];
            rel_out[i * 200 + j] = acc;
        }
    }
}

__global__ __launch_bounds__(256) void bn_apply(
    float* __restrict__ h, const float* __restrict__ scale, const float* __restrict__ shift) {
    __shared__ float ssc[200], ssh[200];
    if (threadIdx.x < 200) { ssc[threadIdx.x] = scale[threadIdx.x]; ssh[threadIdx.x] = shift[threadIdx.x]; }
    __syncthreads();
    const int total4 = N_NODES * 200 / 4;  // 5,000,000 float4
    int stride = gridDim.x * blockDim.x;
    for (int i = blockIdx.x * blockDim.x + threadIdx.x; i < total4; i += stride) {
        int c = (i % 50) * 4;
        float4 v = reinterpret_cast<float4*>(h)[i];
        v.x = v.x * ssc[c + 0] + ssh[c + 0];
        v.y = v.y * ssc[c + 1] + ssh[c + 1];
        v.z = v.z * ssc[c + 2] + ssh[c + 2];
        v.w = v.w * ssc[c + 3] + ssh[c + 3];
        reinterpret_cast<float4*>(h)[i] = v;
    }
}

extern "C" void kernel_launch(void* const* d_in, const int* in_sizes, int n_in,
                              void* d_out, int out_size, void* d_ws, size_t ws_size,
                              hipStream_t stream) {
    const float* x         = (const float*)d_in[0];
    const float* rel_repr  = (const float*)d_in[1];
    const float* edge_norm = (const float*)d_in[2];
    const float* in_w      = (const float*)d_in[3];
    const float* out_w     = (const float*)d_in[4];
    const float* loop_w    = (const float*)d_in[5];
    const float* loop_rel  = (const float*)d_in[6];
    const float* w_rel     = (const float*)d_in[7];
    const float* bn_gamma  = (const float*)d_in[8];
    const float* bn_beta   = (const float*)d_in[9];
    const int* edge_src    = (const int*)d_in[10];
    const int* edge_dst    = (const int*)d_in[11];
    const int* edge_type   = (const int*)d_in[12];

    float* out = (float*)d_out;
    char* ws = (char*)d_ws;
    unsigned short* A  = (unsigned short*)(ws + A_OFF);
    unsigned short* Wt = (unsigned short*)(ws + WT_OFF);
    unsigned* hist     = (unsigned*)(ws + HIST_OFF);
    unsigned* cursor   = (unsigned*)(ws + CURSOR_OFF);
    float* scale       = (float*)(ws + SCALE_OFF);
    float* shift       = (float*)(ws + SHIFT_OFF);
    unsigned* rowptr   = (unsigned*)(ws + ROWPTR_OFF);
    int4* recs         = (int4*)(ws + REC_OFF);
    float* PS          = (float*)(ws + PS_OFF);
    float* PQ          = (float*)(ws + PQ_OFF);

    hipMemsetAsync(ws + ZERO_BASE, 0, ZERO_BYTES, stream);  // hist+cursor
    prep_k<<<PREP_NBLK, 256, 0, stream>>>(x, in_w, out_w, loop_w, loop_rel,
                                          edge_dst, A, Wt, hist);
    scan_all<<<1, 1024, 0, stream>>>(hist, rowptr);
    fill_k<<<1563, 256, 0, stream>>>(edge_dst, edge_src, edge_type, edge_norm,
                                     rowptr, cursor, recs);
    aggregate<<<25000, 256, 0, stream>>>(rel_repr, rowptr, recs, A);
    gemm_nodes<<<GEMM_NBLK, 256, 0, stream>>>(A, Wt, out, PS, PQ);
    bnred_rel<<<400, 256, 0, stream>>>(PS, PQ, bn_gamma, bn_beta, rel_repr, w_rel,
                                       scale, shift, out + 20000000);
    bn_apply<<<1024, 256, 0, stream>>>(out, scale, shift);
}

// Round 5
// 346.584 us; speedup vs baseline: 1.5135x; 1.5135x over previous
//
#include <hip/hip_runtime.h>

#define N_NODES 100000
#define N_EDGES 400000
#define HALF_E  200000
#define BN_EPS  1e-5f

// A_bf layout per node row: [in 200 | out 200 | x 200 | pad 40] = 640 bf16 (1280 B)
// Within each 32-bf16 (64 B) chunk, 16B slot s of row v is stored at physical
// slot s ^ ((v>>1)&3)  -> linear global_load_lds staging + XOR'd ds_read_b128
// gives conflict-free (2-way) LDS reads in the GEMM (rule 21: source-side
// pre-swizzle + same XOR on read).
#define KTOT   640
#define CHUNKS 20
#define GEMM_NBLK 782

// LDS tile per buffer: A [0, 8192) = 128 rows x 64 B, W [8192, 24576) = 16 rows x 1024 B
// (W rows 13-15 staged with in-bounds garbage for uniform 6 loads/wave; never read)
#define LDS_BUF_BYTES 24576
#define LDS_W_OFF     8192

#define XSEG_NBLK 25000
#define PACK_NBLK 520
#define HIST_NBLK 1563
#define PREP_NBLK (XSEG_NBLK + PACK_NBLK + HIST_NBLK)

#define SCAN_NBLK 98                     // 98*1024 >= 100000

typedef __bf16 bf16x8 __attribute__((ext_vector_type(8)));
typedef float  f32x4  __attribute__((ext_vector_type(4)));

// ---- workspace layout (bytes) ----
#define A_OFF      0ull                  // 100000*640*2 = 128,000,000
#define WT_OFF     128000000ull          // 20*208*64 B = 266,240 (chunk-major, pre-swizzled)
#define HIST_OFF   128266240ull          // 100000*4
#define CURSOR_OFF 128666240ull          // 100000*4
#define ZERO_BASE  HIST_OFF
#define ZERO_BYTES 800000ull             // hist+cursor
#define SCALE_OFF  129066240ull          // 200*4
#define SHIFT_OFF  129067040ull          // 200*4
#define ROWPTR_OFF 129069440ull          // 100001*4
#define BSUM_OFF   129469856ull          // 98*4
#define BOFF_OFF   129470248ull          // 98*4
#define REC_OFF    129470640ull          // 400000*16 = 6,400,000 (16B aligned)
#define PS_OFF     135870640ull          // 782*200*4 = 625,600
#define PQ_OFF     136496240ull          // 782*200*4 -> end 137,121,840

static __device__ __forceinline__ unsigned short f2bf(float f) {
    union { float f; unsigned u; } v; v.f = f;
    unsigned u = v.u;
    unsigned r = (u + 0x7fffu + ((u >> 16) & 1u)) >> 16;  // RNE
    return (unsigned short)r;
}
static __device__ __forceinline__ float bf2f(unsigned short s) {
    union { unsigned u; float f; } v; v.u = ((unsigned)s) << 16; return v.f;
}

// physical bf16 offset of logical k within a row, given row swizzle s = (v>>1)&3
static __device__ __forceinline__ int swzk(int k, int s) {
    return (k & ~31) | (k & 7) | ((((k >> 3) & 3) ^ s) << 3);
}

// async global->LDS, 16 B per lane, linear LDS dest (wave-uniform base + lane*16)
static __device__ __forceinline__ void gload16(const void* g, void* l) {
    __builtin_amdgcn_global_load_lds(
        (const __attribute__((address_space(1))) void*)g,
        (__attribute__((address_space(3))) void*)l, 16, 0, 0);
}

// ---- fused prep: [0,25000) swizzled x-segment of A + zero pad;
// ---- [25000,25520) pack Wt; [25520,27083) dst-histogram (hist pre-zeroed by memset) ----
__global__ __launch_bounds__(256) void prep_k(
    const float* __restrict__ x,
    const float* __restrict__ in_w, const float* __restrict__ out_w,
    const float* __restrict__ loop_w, const float* __restrict__ loop_rel,
    const int* __restrict__ edst,
    unsigned short* __restrict__ A, unsigned short* __restrict__ Wt,
    unsigned* __restrict__ hist) {
    int b = blockIdx.x;
    if (b < XSEG_NBLK) {
        int v = b * 4 + (threadIdx.x >> 6);
        int lane = threadIdx.x & 63;
        int s = (v >> 1) & 3;
        unsigned short* ar = A + (size_t)v * KTOT;
        if (lane < 50) {
            float4 xv = *reinterpret_cast<const float4*>(x + v * 200 + lane * 4);
            ushort4 w = make_ushort4(f2bf(xv.x), f2bf(xv.y), f2bf(xv.z), f2bf(xv.w));
            *reinterpret_cast<ushort4*>(ar + swzk(400 + lane * 4, s)) = w;
        }
        if (lane < 10)
            *reinterpret_cast<ushort4*>(ar + swzk(600 + lane * 4, s)) = make_ushort4(0, 0, 0, 0);
    } else if (b < XSEG_NBLK + PACK_NBLK) {
        // Wt layout: [c 20][n 208][slot_phys 4][8 bf16]
        int idx = (b - XSEG_NBLK) * 256 + threadIdx.x;   // 520*256 == 20*208*32
        int e = idx & 7;
        int t = idx >> 3;
        int sp = t & 3;
        int t2 = t >> 2;
        int n = t2 % 208;
        int c = t2 / 208;
        int sl = sp ^ ((n >> 1) & 3);
        int k = c * 32 + sl * 8 + e;
        float v = 0.f;
        if (n < 200) {
            if (k < 200)       v = in_w[k * 200 + n];
            else if (k < 400)  v = out_w[(k - 200) * 200 + n];
            else if (k < 600)  v = loop_w[(k - 400) * 200 + n] * loop_rel[k - 400];
        }
        Wt[idx] = f2bf(v);
    } else {
        int e = (b - XSEG_NBLK - PACK_NBLK) * 256 + threadIdx.x;
        if (e < N_EDGES) atomicAdd(&hist[edst[e]], 1u);
    }
}

// ---- scan pass 1: per-block sums ----
__global__ __launch_bounds__(1024) void scan_part(const unsigned* __restrict__ hist,
                                                  unsigned* __restrict__ bsum) {
    __shared__ unsigned s[1024];
    int idx = blockIdx.x * 1024 + threadIdx.x;
    s[threadIdx.x] = (idx < N_NODES) ? hist[idx] : 0u;
    __syncthreads();
    for (int off = 512; off > 0; off >>= 1) {
        if (threadIdx.x < off) s[threadIdx.x] += s[threadIdx.x + off];
        __syncthreads();
    }
    if (threadIdx.x == 0) bsum[blockIdx.x] = s[0];
}

// ---- scan pass 2: serial exclusive scan of 98 block sums ----
__global__ void scan_top(const unsigned* __restrict__ bsum, unsigned* __restrict__ boff,
                         unsigned* __restrict__ rowptr) {
    if (threadIdx.x == 0) {
        unsigned run = 0;
        for (int b = 0; b < SCAN_NBLK; ++b) { boff[b] = run; run += bsum[b]; }
        rowptr[N_NODES] = N_EDGES;
    }
}

// ---- scan pass 3: intra-block exclusive scan + offset ----
__global__ __launch_bounds__(1024) void scan_low(const unsigned* __restrict__ hist,
                                                 const unsigned* __restrict__ boff,
                                                 unsigned* __restrict__ rowptr) {
    __shared__ unsigned s[1024];
    int idx = blockIdx.x * 1024 + threadIdx.x;
    unsigned own = (idx < N_NODES) ? hist[idx] : 0u;
    s[threadIdx.x] = own;
    __syncthreads();
    for (int off = 1; off < 1024; off <<= 1) {
        unsigned t = 0;
        if ((int)threadIdx.x >= off) t = s[threadIdx.x - off];
        __syncthreads();
        if ((int)threadIdx.x >= off) s[threadIdx.x] += t;
        __syncthreads();
    }
    if (idx < N_NODES) rowptr[idx] = boff[blockIdx.x] + s[threadIdx.x] - own;
}

// ---- CSR fill: packed edge records {src, type, norm, dir} at sorted positions ----
__global__ __launch_bounds__(256) void fill_k(
    const int* __restrict__ edst, const int* __restrict__ esrc,
    const int* __restrict__ etyp, const float* __restrict__ norm,
    const unsigned* __restrict__ rowptr, unsigned* __restrict__ cursor,
    int4* __restrict__ recs) {
    int e = blockIdx.x * 256 + threadIdx.x;
    if (e < N_EDGES) {
        int d = edst[e];
        unsigned pos = rowptr[d] + atomicAdd(&cursor[d], 1u);
        recs[pos] = make_int4(esrc[e], etyp[e], __float_as_int(norm[e]), (e < HALF_E) ? 1 : 0);
    }
}

// ---- gather aggregation: one wave per dst node; swizzled bf16 x-rows ----
// 4 edges in flight per iteration (8 outstanding VMEM) to cover gather latency.
__global__ __launch_bounds__(256) void aggregate(
    const float* __restrict__ rel, const unsigned* __restrict__ rowptr,
    const int4* __restrict__ recs, unsigned short* __restrict__ A) {
    int v = blockIdx.x * 4 + (threadIdx.x >> 6);
    int lane = threadIdx.x & 63;
    bool act = lane < 50;                    // lane owns dims [lane*4, lane*4+4)
    int col = lane * 4;
    int kx = 400 + col;                      // logical x position
    int kxb = (kx & ~31) | (kx & 7);         // swizzle-invariant part
    int kxs = (kx >> 3) & 3;                 // logical slot
    float4 aI = make_float4(0.f, 0.f, 0.f, 0.f);
    float4 aO = make_float4(0.f, 0.f, 0.f, 0.f);

    const unsigned short* __restrict__ Ab = A;
    auto xload = [&](int src) -> ushort4 {
        int s = (src >> 1) & 3;
        return *reinterpret_cast<const ushort4*>(
            Ab + (size_t)src * KTOT + kxb + ((kxs ^ s) << 3));
    };
    auto accum = [&](const int4& r, const ushort4& xv, const float4& rl) {
        float nz = __int_as_float(r.z);
        float mx = bf2f(xv.x) * rl.x * nz;
        float my = bf2f(xv.y) * rl.y * nz;
        float mz = bf2f(xv.z) * rl.z * nz;
        float mw = bf2f(xv.w) * rl.w * nz;
        if (r.w) { aI.x += mx; aI.y += my; aI.z += mz; aI.w += mw; }
        else     { aO.x += mx; aO.y += my; aO.z += mz; aO.w += mw; }
    };

    int beg = rowptr[v], end = rowptr[v + 1];
    int j = beg;
    for (; j + 3 < end; j += 4) {
        int4 r0 = recs[j];
        int4 r1 = recs[j + 1];
        int4 r2 = recs[j + 2];
        int4 r3 = recs[j + 3];
        if (act) {
            ushort4 x0 = xload(r0.x);
            ushort4 x1 = xload(r1.x);
            ushort4 x2 = xload(r2.x);
            ushort4 x3 = xload(r3.x);
            float4 rl0 = *reinterpret_cast<const float4*>(rel + r0.y * 200 + col);
            float4 rl1 = *reinterpret_cast<const float4*>(rel + r1.y * 200 + col);
            float4 rl2 = *reinterpret_cast<const float4*>(rel + r2.y * 200 + col);
            float4 rl3 = *reinterpret_cast<const float4*>(rel + r3.y * 200 + col);
            accum(r0, x0, rl0);
            accum(r1, x1, rl1);
            accum(r2, x2, rl2);
            accum(r3, x3, rl3);
        }
    }
    if (j + 1 < end) {
        int4 r0 = recs[j];
        int4 r1 = recs[j + 1];
        if (act) {
            ushort4 x0 = xload(r0.x);
            ushort4 x1 = xload(r1.x);
            float4 rl0 = *reinterpret_cast<const float4*>(rel + r0.y * 200 + col);
            float4 rl1 = *reinterpret_cast<const float4*>(rel + r1.y * 200 + col);
            accum(r0, x0, rl0);
            accum(r1, x1, rl1);
        }
        j += 2;
    }
    if (j < end) {
        int4 r0 = recs[j];
        if (act) {
            ushort4 x0 = xload(r0.x);
            float4 rl0 = *reinterpret_cast<const float4*>(rel + r0.y * 200 + col);
            accum(r0, x0, rl0);
        }
    }
    if (act) {
        int sv = (v >> 1) & 3;
        unsigned short* ar = A + (size_t)v * KTOT;
        ushort4 wI = make_ushort4(f2bf(aI.x), f2bf(aI.y), f2bf(aI.z), f2bf(aI.w));
        ushort4 wO = make_ushort4(f2bf(aO.x), f2bf(aO.y), f2bf(aO.z), f2bf(aO.w));
        *reinterpret_cast<ushort4*>(ar + swzk(col, sv))       = wI;
        *reinterpret_cast<ushort4*>(ar + swzk(200 + col, sv)) = wO;
    }
}

// ---- GEMM: out[v][n] = A_bf[v][:] . Wt[n][:] / 3 ; per-block BN partials ----
// Counted-vmcnt pipeline (guide T4): stage 2 chunks ahead (12 loads in flight),
// raw s_barrier + s_waitcnt vmcnt(6) per chunk -> next chunk's prefetch is
// NEVER drained by a barrier. Uniform 6 loads/wave/chunk (2 A + 4 W; W rows
// 13-15 are in-bounds garbage, never read by MFMA).
__global__ __launch_bounds__(256) void gemm_nodes(
    const unsigned short* __restrict__ A, const unsigned short* __restrict__ Wt,
    float* __restrict__ out, float* __restrict__ PS, float* __restrict__ PQ) {
    __shared__ __align__(16) char lds[2][LDS_BUF_BYTES];
    int tid = threadIdx.x;
    int wave = tid >> 6, lane = tid & 63;
    int quad = lane >> 4, l15 = lane & 15;
    int row0 = blockIdx.x * 128;
    int pslot16 = ((quad ^ ((l15 >> 1) & 3)) << 4);   // physical 16B slot for reads

    // staging sources: wave stages A rows [(wave*2+p)*16, +16), lane -> (row lane>>2, slot lane&3)
    int sv0 = row0 + (wave * 2 + 0) * 16 + (lane >> 2);
    int sv1 = row0 + (wave * 2 + 1) * 16 + (lane >> 2);
    if (sv0 >= N_NODES) sv0 = N_NODES - 1;   // clamp; excluded from out/stats below
    if (sv1 >= N_NODES) sv1 = N_NODES - 1;
    const char* Ab = (const char*)A;
    const char* srcA0 = Ab + (size_t)sv0 * 1280 + (lane & 3) * 16;
    const char* srcA1 = Ab + (size_t)sv1 * 1280 + (lane & 3) * 16;
    const char* Wb = (const char*)Wt + lane * 16;

    // LDS read offsets
    int rdA0 = ((wave * 2 + 0) * 16 + l15) * 64 + pslot16;
    int rdA1 = ((wave * 2 + 1) * 16 + l15) * 64 + pslot16;
    int rdB  = LDS_W_OFF + l15 * 64 + pslot16;

    f32x4 acc[2][13];
#pragma unroll
    for (int i = 0; i < 2; ++i)
#pragma unroll
        for (int j = 0; j < 13; ++j) {
            acc[i][j].x = 0.f; acc[i][j].y = 0.f; acc[i][j].z = 0.f; acc[i][j].w = 0.f;
        }

    // stage chunk c into buffer lb: exactly 6 loads per wave
    auto stage = [&](int c, char* lb) {
        gload16(srcA0 + c * 64, lb + (wave * 2 + 0) * 1024);
        gload16(srcA1 + c * 64, lb + (wave * 2 + 1) * 1024);
        const char* wsrc = Wb + (size_t)c * 13312;
#pragma unroll
        for (int i = 0; i < 4; ++i) {
            int r = wave + i * 4;                 // LDS W row 0..15
            int srcr = (r < 13) ? r : (r - 13);   // in-bounds garbage for 13..15
            gload16(wsrc + srcr * 1024, lb + LDS_W_OFF + r * 1024);
        }
    };

    stage(0, lds[0]);
    stage(1, lds[1]);

#pragma unroll
    for (int c = 0; c < CHUNKS; ++c) {
        char* lb = lds[c & 1];
        if (c < CHUNKS - 1) {
            asm volatile("s_waitcnt vmcnt(6)" ::: "memory");   // chunk c's 6 done
        } else {
            asm volatile("s_waitcnt vmcnt(0)" ::: "memory");
        }
        __builtin_amdgcn_sched_barrier(0);
        __builtin_amdgcn_s_barrier();       // all waves' chunk-c data in LDS
        __builtin_amdgcn_sched_barrier(0);
        bf16x8 a0 = *reinterpret_cast<const bf16x8*>(lb + rdA0);
        bf16x8 a1 = *reinterpret_cast<const bf16x8*>(lb + rdA1);
#pragma unroll
        for (int nt = 0; nt < 13; ++nt) {
            bf16x8 b = *reinterpret_cast<const bf16x8*>(lb + rdB + nt * 1024);
            acc[0][nt] = __builtin_amdgcn_mfma_f32_16x16x32_bf16(a0, b, acc[0][nt], 0, 0, 0);
            acc[1][nt] = __builtin_amdgcn_mfma_f32_16x16x32_bf16(a1, b, acc[1][nt], 0, 0, 0);
        }
        __builtin_amdgcn_s_barrier();       // all waves done reading lb
        __builtin_amdgcn_sched_barrier(0);
        if (c + 2 < CHUNKS) stage(c + 2, lb);
    }

    // epilogue: store /3; per-wave column stats -> LDS -> per-block partials
    float* redS = reinterpret_cast<float*>(lds[0]);        // [4][200]
    float* redQ = reinterpret_cast<float*>(lds[0]) + 800;  // [4][200]
#pragma unroll
    for (int nt = 0; nt < 13; ++nt) {
        int n = nt * 16 + l15;
        float s = 0.f, q = 0.f;
#pragma unroll
        for (int i = 0; i < 2; ++i) {
            int mbase = row0 + (wave * 2 + i) * 16 + quad * 4;
#pragma unroll
            for (int r = 0; r < 4; ++r) {
                float val = acc[i][nt][r] * (1.f / 3.f);
                int m = mbase + r;
                if (m < N_NODES) {
                    if (n < 200) out[m * 200 + n] = val;
                    s += val; q += val * val;
                }
            }
        }
        s += __shfl_xor(s, 16); s += __shfl_xor(s, 32);
        q += __shfl_xor(q, 16); q += __shfl_xor(q, 32);
        if (lane < 16 && n < 200) {
            redS[wave * 200 + n] = s;
            redQ[wave * 200 + n] = q;
        }
    }
    __syncthreads();
    if (tid < 200) {
        float s = redS[tid] + redS[200 + tid] + redS[400 + tid] + redS[600 + tid];
        float q = redQ[tid] + redQ[200 + tid] + redQ[400 + tid] + redQ[600 + tid];
        PS[blockIdx.x * 200 + tid] = s;
        PQ[blockIdx.x * 200 + tid] = q;
    }
}

// ---- fused: blocks [0,200) BN-reduce per column; blocks [200,400) rel_out rows ----
__global__ __launch_bounds__(256) void bnred_rel(
    const float* __restrict__ PS, const float* __restrict__ PQ,
    const float* __restrict__ gamma, const float* __restrict__ beta,
    const float* __restrict__ rel, const float* __restrict__ w,
    float* __restrict__ scale, float* __restrict__ shift,
    float* __restrict__ rel_out) {
    if (blockIdx.x < 200) {
        __shared__ float ls[256], lq[256];
        int c = blockIdx.x;
        float s = 0.f, q = 0.f;
        for (int b = threadIdx.x; b < GEMM_NBLK; b += 256) {
            s += PS[b * 200 + c];
            q += PQ[b * 200 + c];
        }
        ls[threadIdx.x] = s; lq[threadIdx.x] = q;
        __syncthreads();
        for (int off = 128; off > 0; off >>= 1) {
            if (threadIdx.x < off) {
                ls[threadIdx.x] += ls[threadIdx.x + off];
                lq[threadIdx.x] += lq[threadIdx.x + off];
            }
            __syncthreads();
        }
        if (threadIdx.x == 0) {
            float mean = ls[0] * (1.f / N_NODES);
            float var = lq[0] * (1.f / N_NODES) - mean * mean;
            float inv = rsqrtf(var + BN_EPS);
            float sc = inv * gamma[c];
            scale[c] = sc;
            shift[c] = beta[c] - mean * sc;
        }
    } else {
        int i = blockIdx.x - 200, j = threadIdx.x;
        if (j < 200) {
            float acc = 0.f;
            for (int k = 0; k < 200; ++k) acc += rel[i * 200 + k] * w[k * 200 + j];
            rel_out[i * 200 + j] = acc;
        }
    }
}

__global__ __launch_bounds__(256) void bn_apply(
    float* __restrict__ h, const float* __restrict__ scale, const float* __restrict__ shift) {
    __shared__ float ssc[200], ssh[200];
    if (threadIdx.x < 200) { ssc[threadIdx.x] = scale[threadIdx.x]; ssh[threadIdx.x] = shift[threadIdx.x]; }
    __syncthreads();
    const int total4 = N_NODES * 200 / 4;  // 5,000,000 float4
    int stride = gridDim.x * blockDim.x;
    for (int i = blockIdx.x * blockDim.x + threadIdx.x; i < total4; i += stride) {
        int c = (i % 50) * 4;
        float4 v = reinterpret_cast<float4*>(h)[i];
        v.x = v.x * ssc[c + 0] + ssh[c + 0];
        v.y = v.y * ssc[c + 1] + ssh[c + 1];
        v.z = v.z * ssc[c + 2] + ssh[c + 2];
        v.w = v.w * ssc[c + 3] + ssh[c + 3];
        reinterpret_cast<float4*>(h)[i] = v;
    }
}

extern "C" void kernel_launch(void* const* d_in, const int* in_sizes, int n_in,
                              void* d_out, int out_size, void* d_ws, size_t ws_size,
                              hipStream_t stream) {
    const float* x         = (const float*)d_in[0];
    const float* rel_repr  = (const float*)d_in[1];
    const float* edge_norm = (const float*)d_in[2];
    const float* in_w      = (const float*)d_in[3];
    const float* out_w     = (const float*)d_in[4];
    const float* loop_w    = (const float*)d_in[5];
    const float* loop_rel  = (const float*)d_in[6];
    const float* w_rel     = (const float*)d_in[7];
    const float* bn_gamma  = (const float*)d_in[8];
    const float* bn_beta   = (const float*)d_in[9];
    const int* edge_src    = (const int*)d_in[10];
    const int* edge_dst    = (const int*)d_in[11];
    const int* edge_type   = (const int*)d_in[12];

    float* out = (float*)d_out;
    char* ws = (char*)d_ws;
    unsigned short* A  = (unsigned short*)(ws + A_OFF);
    unsigned short* Wt = (unsigned short*)(ws + WT_OFF);
    unsigned* hist     = (unsigned*)(ws + HIST_OFF);
    unsigned* cursor   = (unsigned*)(ws + CURSOR_OFF);
    float* scale       = (float*)(ws + SCALE_OFF);
    float* shift       = (float*)(ws + SHIFT_OFF);
    unsigned* rowptr   = (unsigned*)(ws + ROWPTR_OFF);
    unsigned* bsum     = (unsigned*)(ws + BSUM_OFF);
    unsigned* boff     = (unsigned*)(ws + BOFF_OFF);
    int4* recs         = (int4*)(ws + REC_OFF);
    float* PS          = (float*)(ws + PS_OFF);
    float* PQ          = (float*)(ws + PQ_OFF);

    hipMemsetAsync(ws + ZERO_BASE, 0, ZERO_BYTES, stream);  // hist+cursor
    prep_k<<<PREP_NBLK, 256, 0, stream>>>(x, in_w, out_w, loop_w, loop_rel,
                                          edge_dst, A, Wt, hist);
    scan_part<<<SCAN_NBLK, 1024, 0, stream>>>(hist, bsum);
    scan_top<<<1, 64, 0, stream>>>(bsum, boff, rowptr);
    scan_low<<<SCAN_NBLK, 1024, 0, stream>>>(hist, boff, rowptr);
    fill_k<<<1563, 256, 0, stream>>>(edge_dst, edge_src, edge_type, edge_norm,
                                     rowptr, cursor, recs);
    aggregate<<<25000, 256, 0, stream>>>(rel_repr, rowptr, recs, A);
    gemm_nodes<<<GEMM_NBLK, 256, 0, stream>>>(A, Wt, out, PS, PQ);
    bnred_rel<<<400, 256, 0, stream>>>(PS, PQ, bn_gamma, bn_beta, rel_repr, w_rel,
                                       scale, shift, out + 20000000);
    bn_apply<<<1024, 256, 0, stream>>>(out, scale, shift);
}

// Round 8
// 344.428 us; speedup vs baseline: 1.5229x; 1.0063x over previous
//
#include <hip/hip_runtime.h>

#define N_NODES 100000
#define N_EDGES 400000
#define HALF_E  200000
#define BN_EPS  1e-5f

// A_bf layout per node row: [in 200 | out 200 | x 200 | pad 40] = 640 bf16 (1280 B)
// Within each 32-bf16 (64 B) chunk, 16B slot s of row v is stored at physical
// slot s ^ ((v>>1)&3)  -> linear global_load_lds staging + XOR'd ds_read_b128
// gives conflict-free (2-way) LDS reads in the GEMM (rule 21).
// AFTER the gemm k-loop, each tile-block overwrites slots [0,200) of its OWN
// rows with bf16 h (rows are tile-exclusive at that point) -> bn_apply reads
// 40 MB bf16 instead of 80 MB f32, and gemm writes 40 MB instead of 80 MB.
#define KTOT   640
#define CHUNKS 20
#define GEMM_NBLK 782

// LDS tile per buffer: A [0, 8192) = 128 rows x 64 B, W [8192, 24576) = 16 rows x 1024 B
// (W rows 13-15 staged with in-bounds garbage for uniform 6 loads/wave; never read)
#define LDS_BUF_BYTES 24576
#define LDS_W_OFF     8192

#define XSEG_NBLK 25000
#define PACK_NBLK 520
#define HIST_NBLK 1563
#define PREP_NBLK (XSEG_NBLK + PACK_NBLK + HIST_NBLK)

#define SCAN_NBLK 98                     // 98*1024 >= 100000

typedef __bf16 bf16x8 __attribute__((ext_vector_type(8)));
typedef float  f32x4  __attribute__((ext_vector_type(4)));

// ---- workspace layout (bytes) ----
#define A_OFF      0ull                  // 100000*640*2 = 128,000,000
#define WT_OFF     128000000ull          // 20*208*64 B = 266,240 (chunk-major, pre-swizzled)
#define HIST_OFF   128266240ull          // 100000*4
#define CURSOR_OFF 128666240ull          // 100000*4
#define ZERO_BASE  HIST_OFF
#define ZERO_BYTES 800000ull             // hist+cursor
#define SCALE_OFF  129066240ull          // 200*4
#define SHIFT_OFF  129067040ull          // 200*4
#define ROWPTR_OFF 129069440ull          // 100001*4
#define BSUM_OFF   129469856ull          // 98*4
#define REC_OFF    129470640ull          // 400000*16 = 6,400,000 (16B aligned)
#define PS_OFF     135870640ull          // 782*200*4 = 625,600
#define PQ_OFF     136496240ull          // 782*200*4 -> end 137,121,840

static __device__ __forceinline__ unsigned short f2bf(float f) {
    union { float f; unsigned u; } v; v.f = f;
    unsigned u = v.u;
    unsigned r = (u + 0x7fffu + ((u >> 16) & 1u)) >> 16;  // RNE
    return (unsigned short)r;
}
static __device__ __forceinline__ float bf2f(unsigned short s) {
    union { unsigned u; float f; } v; v.u = ((unsigned)s) << 16; return v.f;
}

// physical bf16 offset of logical k within a row, given row swizzle s = (v>>1)&3
static __device__ __forceinline__ int swzk(int k, int s) {
    return (k & ~31) | (k & 7) | ((((k >> 3) & 3) ^ s) << 3);
}

// async global->LDS, 16 B per lane, linear LDS dest (wave-uniform base + lane*16)
static __device__ __forceinline__ void gload16(const void* g, void* l) {
    __builtin_amdgcn_global_load_lds(
        (const __attribute__((address_space(1))) void*)g,
        (__attribute__((address_space(3))) void*)l, 16, 0, 0);
}

// ---- fused prep: [0,25000) swizzled x-segment of A + zero pad;
// ---- [25000,25520) pack Wt; [25520,27083) dst-histogram (hist pre-zeroed) ----
__global__ __launch_bounds__(256) void prep_k(
    const float* __restrict__ x,
    const float* __restrict__ in_w, const float* __restrict__ out_w,
    const float* __restrict__ loop_w, const float* __restrict__ loop_rel,
    const int* __restrict__ edst,
    unsigned short* __restrict__ A, unsigned short* __restrict__ Wt,
    unsigned* __restrict__ hist) {
    int b = blockIdx.x;
    if (b < XSEG_NBLK) {
        int v = b * 4 + (threadIdx.x >> 6);
        int lane = threadIdx.x & 63;
        int s = (v >> 1) & 3;
        unsigned short* ar = A + (size_t)v * KTOT;
        if (lane < 50) {
            float4 xv = *reinterpret_cast<const float4*>(x + v * 200 + lane * 4);
            ushort4 w = make_ushort4(f2bf(xv.x), f2bf(xv.y), f2bf(xv.z), f2bf(xv.w));
            *reinterpret_cast<ushort4*>(ar + swzk(400 + lane * 4, s)) = w;
        }
        if (lane < 10)
            *reinterpret_cast<ushort4*>(ar + swzk(600 + lane * 4, s)) = make_ushort4(0, 0, 0, 0);
    } else if (b < XSEG_NBLK + PACK_NBLK) {
        // Wt layout: [c 20][n 208][slot_phys 4][8 bf16]
        int idx = (b - XSEG_NBLK) * 256 + threadIdx.x;   // 520*256 == 20*208*32
        int e = idx & 7;
        int t = idx >> 3;
        int sp = t & 3;
        int t2 = t >> 2;
        int n = t2 % 208;
        int c = t2 / 208;
        int sl = sp ^ ((n >> 1) & 3);
        int k = c * 32 + sl * 8 + e;
        float v = 0.f;
        if (n < 200) {
            if (k < 200)       v = in_w[k * 200 + n];
            else if (k < 400)  v = out_w[(k - 200) * 200 + n];
            else if (k < 600)  v = loop_w[(k - 400) * 200 + n] * loop_rel[k - 400];
        }
        Wt[idx] = f2bf(v);
    } else {
        int e = (b - XSEG_NBLK - PACK_NBLK) * 256 + threadIdx.x;
        if (e < N_EDGES) atomicAdd(&hist[edst[e]], 1u);
    }
}

// ---- scan pass 1: per-block sums ----
__global__ __launch_bounds__(1024) void scan_part(const unsigned* __restrict__ hist,
                                                  unsigned* __restrict__ bsum) {
    __shared__ unsigned s[1024];
    int idx = blockIdx.x * 1024 + threadIdx.x;
    s[threadIdx.x] = (idx < N_NODES) ? hist[idx] : 0u;
    __syncthreads();
    for (int off = 512; off > 0; off >>= 1) {
        if (threadIdx.x < off) s[threadIdx.x] += s[threadIdx.x + off];
        __syncthreads();
    }
    if (threadIdx.x == 0) bsum[blockIdx.x] = s[0];
}

// ---- scan pass 2 (merged top+low): intra-block exclusive scan + own block
// ---- offset computed from bsum in-kernel (<=97 uniform LDS adds) ----
__global__ __launch_bounds__(1024) void scan_low(const unsigned* __restrict__ hist,
                                                 const unsigned* __restrict__ bsum,
                                                 unsigned* __restrict__ rowptr) {
    __shared__ unsigned s[1024];
    __shared__ unsigned bs[128];
    int bid = blockIdx.x;
    if (threadIdx.x < 128)
        bs[threadIdx.x] = (threadIdx.x < SCAN_NBLK) ? bsum[threadIdx.x] : 0u;
    int idx = bid * 1024 + threadIdx.x;
    unsigned own = (idx < N_NODES) ? hist[idx] : 0u;
    s[threadIdx.x] = own;
    __syncthreads();
    unsigned boff = 0;
    for (int j = 0; j < bid; ++j) boff += bs[j];   // uniform loop, redundant per thread
    for (int off = 1; off < 1024; off <<= 1) {
        unsigned t = 0;
        if ((int)threadIdx.x >= off) t = s[threadIdx.x - off];
        __syncthreads();
        if ((int)threadIdx.x >= off) s[threadIdx.x] += t;
        __syncthreads();
    }
    if (idx < N_NODES) rowptr[idx] = boff + s[threadIdx.x] - own;
    if (bid == 0 && threadIdx.x == 0) rowptr[N_NODES] = N_EDGES;
}

// ---- CSR fill: packed edge records {src, type, norm, dir} at sorted positions ----
__global__ __launch_bounds__(256) void fill_k(
    const int* __restrict__ edst, const int* __restrict__ esrc,
    const int* __restrict__ etyp, const float* __restrict__ norm,
    const unsigned* __restrict__ rowptr, unsigned* __restrict__ cursor,
    int4* __restrict__ recs) {
    int e = blockIdx.x * 256 + threadIdx.x;
    if (e < N_EDGES) {
        int d = edst[e];
        unsigned pos = rowptr[d] + atomicAdd(&cursor[d], 1u);
        recs[pos] = make_int4(esrc[e], etyp[e], __float_as_int(norm[e]), (e < HALF_E) ? 1 : 0);
    }
}

// ---- gather aggregation: one wave per dst node; swizzled bf16 x-rows ----
// 4 edges in flight per iteration (8 outstanding VMEM) to cover gather latency.
__global__ __launch_bounds__(256) void aggregate(
    const float* __restrict__ rel, const unsigned* __restrict__ rowptr,
    const int4* __restrict__ recs, unsigned short* __restrict__ A) {
    int v = blockIdx.x * 4 + (threadIdx.x >> 6);
    int lane = threadIdx.x & 63;
    bool act = lane < 50;                    // lane owns dims [lane*4, lane*4+4)
    int col = lane * 4;
    int kx = 400 + col;                      // logical x position
    int kxb = (kx & ~31) | (kx & 7);         // swizzle-invariant part
    int kxs = (kx >> 3) & 3;                 // logical slot
    float4 aI = make_float4(0.f, 0.f, 0.f, 0.f);
    float4 aO = make_float4(0.f, 0.f, 0.f, 0.f);

    const unsigned short* __restrict__ Ab = A;
    auto xload = [&](int src) -> ushort4 {
        int s = (src >> 1) & 3;
        return *reinterpret_cast<const ushort4*>(
            Ab + (size_t)src * KTOT + kxb + ((kxs ^ s) << 3));
    };
    auto accum = [&](const int4& r, const ushort4& xv, const float4& rl) {
        float nz = __int_as_float(r.z);
        float mx = bf2f(xv.x) * rl.x * nz;
        float my = bf2f(xv.y) * rl.y * nz;
        float mz = bf2f(xv.z) * rl.z * nz;
        float mw = bf2f(xv.w) * rl.w * nz;
        if (r.w) { aI.x += mx; aI.y += my; aI.z += mz; aI.w += mw; }
        else     { aO.x += mx; aO.y += my; aO.z += mz; aO.w += mw; }
    };

    int beg = rowptr[v], end = rowptr[v + 1];
    int j = beg;
    for (; j + 3 < end; j += 4) {
        int4 r0 = recs[j];
        int4 r1 = recs[j + 1];
        int4 r2 = recs[j + 2];
        int4 r3 = recs[j + 3];
        if (act) {
            ushort4 x0 = xload(r0.x);
            ushort4 x1 = xload(r1.x);
            ushort4 x2 = xload(r2.x);
            ushort4 x3 = xload(r3.x);
            float4 rl0 = *reinterpret_cast<const float4*>(rel + r0.y * 200 + col);
            float4 rl1 = *reinterpret_cast<const float4*>(rel + r1.y * 200 + col);
            float4 rl2 = *reinterpret_cast<const float4*>(rel + r2.y * 200 + col);
            float4 rl3 = *reinterpret_cast<const float4*>(rel + r3.y * 200 + col);
            accum(r0, x0, rl0);
            accum(r1, x1, rl1);
            accum(r2, x2, rl2);
            accum(r3, x3, rl3);
        }
    }
    if (j + 1 < end) {
        int4 r0 = recs[j];
        int4 r1 = recs[j + 1];
        if (act) {
            ushort4 x0 = xload(r0.x);
            ushort4 x1 = xload(r1.x);
            float4 rl0 = *reinterpret_cast<const float4*>(rel + r0.y * 200 + col);
            float4 rl1 = *reinterpret_cast<const float4*>(rel + r1.y * 200 + col);
            accum(r0, x0, rl0);
            accum(r1, x1, rl1);
        }
        j += 2;
    }
    if (j < end) {
        int4 r0 = recs[j];
        if (act) {
            ushort4 x0 = xload(r0.x);
            float4 rl0 = *reinterpret_cast<const float4*>(rel + r0.y * 200 + col);
            accum(r0, x0, rl0);
        }
    }
    if (act) {
        int sv = (v >> 1) & 3;
        unsigned short* ar = A + (size_t)v * KTOT;
        ushort4 wI = make_ushort4(f2bf(aI.x), f2bf(aI.y), f2bf(aI.z), f2bf(aI.w));
        ushort4 wO = make_ushort4(f2bf(aO.x), f2bf(aO.y), f2bf(aO.z), f2bf(aO.w));
        *reinterpret_cast<ushort4*>(ar + swzk(col, sv))       = wI;
        *reinterpret_cast<ushort4*>(ar + swzk(200 + col, sv)) = wO;
    }
}

// ---- GEMM: h[v][n] = A_bf[v][:] . Wt[n][:] / 3 ; per-block BN partials ----
// Counted-vmcnt pipeline (round-5 verified). Epilogue stores h as bf16
// IN-PLACE into A's own rows (tile-exclusive after the k-loop) -> halves
// the write traffic and lets bn_apply read bf16.
__global__ __launch_bounds__(256) void gemm_nodes(
    unsigned short* __restrict__ A, const unsigned short* __restrict__ Wt,
    float* __restrict__ PS, float* __restrict__ PQ) {
    __shared__ __align__(16) char lds[2][LDS_BUF_BYTES];
    int tid = threadIdx.x;
    int wave = tid >> 6, lane = tid & 63;
    int quad = lane >> 4, l15 = lane & 15;
    int row0 = blockIdx.x * 128;
    int pslot16 = ((quad ^ ((l15 >> 1) & 3)) << 4);   // physical 16B slot for reads

    int sv0 = row0 + (wave * 2 + 0) * 16 + (lane >> 2);
    int sv1 = row0 + (wave * 2 + 1) * 16 + (lane >> 2);
    if (sv0 >= N_NODES) sv0 = N_NODES - 1;   // clamp; excluded from stats below
    if (sv1 >= N_NODES) sv1 = N_NODES - 1;
    const char* Ab = (const char*)A;
    const char* srcA0 = Ab + (size_t)sv0 * 1280 + (lane & 3) * 16;
    const char* srcA1 = Ab + (size_t)sv1 * 1280 + (lane & 3) * 16;
    const char* Wb = (const char*)Wt + lane * 16;

    int rdA0 = ((wave * 2 + 0) * 16 + l15) * 64 + pslot16;
    int rdA1 = ((wave * 2 + 1) * 16 + l15) * 64 + pslot16;
    int rdB  = LDS_W_OFF + l15 * 64 + pslot16;

    f32x4 acc[2][13];
#pragma unroll
    for (int i = 0; i < 2; ++i)
#pragma unroll
        for (int j = 0; j < 13; ++j) {
            acc[i][j].x = 0.f; acc[i][j].y = 0.f; acc[i][j].z = 0.f; acc[i][j].w = 0.f;
        }

    // stage chunk c into buffer lb: exactly 6 loads per wave
    auto stage = [&](int c, char* lb) {
        gload16(srcA0 + c * 64, lb + (wave * 2 + 0) * 1024);
        gload16(srcA1 + c * 64, lb + (wave * 2 + 1) * 1024);
        const char* wsrc = Wb + (size_t)c * 13312;
#pragma unroll
        for (int i = 0; i < 4; ++i) {
            int r = wave + i * 4;                 // LDS W row 0..15
            int srcr = (r < 13) ? r : (r - 13);   // in-bounds garbage for 13..15
            gload16(wsrc + srcr * 1024, lb + LDS_W_OFF + r * 1024);
        }
    };

    stage(0, lds[0]);
    stage(1, lds[1]);

#pragma unroll
    for (int c = 0; c < CHUNKS; ++c) {
        char* lb = lds[c & 1];
        if (c < CHUNKS - 1) {
            asm volatile("s_waitcnt vmcnt(6)" ::: "memory");   // chunk c's 6 done
        } else {
            asm volatile("s_waitcnt vmcnt(0)" ::: "memory");
        }
        __builtin_amdgcn_sched_barrier(0);
        __builtin_amdgcn_s_barrier();       // all waves' chunk-c data in LDS
        __builtin_amdgcn_sched_barrier(0);
        bf16x8 a0 = *reinterpret_cast<const bf16x8*>(lb + rdA0);
        bf16x8 a1 = *reinterpret_cast<const bf16x8*>(lb + rdA1);
#pragma unroll
        for (int nt = 0; nt < 13; ++nt) {
            bf16x8 b = *reinterpret_cast<const bf16x8*>(lb + rdB + nt * 1024);
            acc[0][nt] = __builtin_amdgcn_mfma_f32_16x16x32_bf16(a0, b, acc[0][nt], 0, 0, 0);
            acc[1][nt] = __builtin_amdgcn_mfma_f32_16x16x32_bf16(a1, b, acc[1][nt], 0, 0, 0);
        }
        __builtin_amdgcn_s_barrier();       // all waves done reading lb
        __builtin_amdgcn_sched_barrier(0);
        if (c + 2 < CHUNKS) stage(c + 2, lb);
    }

    // epilogue: store h bf16 in-place; per-wave column stats -> per-block partials
    float* redS = reinterpret_cast<float*>(lds[0]);        // [4][200]
    float* redQ = reinterpret_cast<float*>(lds[0]) + 800;  // [4][200]
#pragma unroll
    for (int nt = 0; nt < 13; ++nt) {
        int n = nt * 16 + l15;
        float s = 0.f, q = 0.f;
#pragma unroll
        for (int i = 0; i < 2; ++i) {
            int mbase = row0 + (wave * 2 + i) * 16 + quad * 4;
#pragma unroll
            for (int r = 0; r < 4; ++r) {
                float val = acc[i][nt][r] * (1.f / 3.f);
                int m = mbase + r;
                if (m < N_NODES) {
                    if (n < 200) A[(size_t)m * KTOT + n] = f2bf(val);
                    s += val; q += val * val;
                }
            }
        }
        s += __shfl_xor(s, 16); s += __shfl_xor(s, 32);
        q += __shfl_xor(q, 16); q += __shfl_xor(q, 32);
        if (lane < 16 && n < 200) {
            redS[wave * 200 + n] = s;
            redQ[wave * 200 + n] = q;
        }
    }
    __syncthreads();
    if (tid < 200) {
        float s = redS[tid] + redS[200 + tid] + redS[400 + tid] + redS[600 + tid];
        float q = redQ[tid] + redQ[200 + tid] + redQ[400 + tid] + redQ[600 + tid];
        PS[blockIdx.x * 200 + tid] = s;
        PQ[blockIdx.x * 200 + tid] = q;
    }
}

// ---- fused: blocks [0,200) BN-reduce per column; blocks [200,400) rel_out rows ----
__global__ __launch_bounds__(256) void bnred_rel(
    const float* __restrict__ PS, const float* __restrict__ PQ,
    const float* __restrict__ gamma, const float* __restrict__ beta,
    const float* __restrict__ rel, const float* __restrict__ w,
    float* __restrict__ scale, float* __restrict__ shift,
    float* __restrict__ rel_out) {
    if (blockIdx.x < 200) {
        __shared__ float ls[256], lq[256];
        int c = blockIdx.x;
        float s = 0.f, q = 0.f;
        for (int b = threadIdx.x; b < GEMM_NBLK; b += 256) {
            s += PS[b * 200 + c];
            q += PQ[b * 200 + c];
        }
        ls[threadIdx.x] = s; lq[threadIdx.x] = q;
        __syncthreads();
        for (int off = 128; off > 0; off >>= 1) {
            if (threadIdx.x < off) {
                ls[threadIdx.x] += ls[threadIdx.x + off];
                lq[threadIdx.x] += lq[threadIdx.x + off];
            }
            __syncthreads();
        }
        if (threadIdx.x == 0) {
            float mean = ls[0] * (1.f / N_NODES);
            float var = lq[0] * (1.f / N_NODES) - mean * mean;
            float inv = rsqrtf(var + BN_EPS);
            float sc = inv * gamma[c];
            scale[c] = sc;
            shift[c] = beta[c] - mean * sc;
        }
    } else {
        int i = blockIdx.x - 200, j = threadIdx.x;
        if (j < 200) {
            float acc = 0.f;
            for (int k = 0; k < 200; ++k) acc += rel[i * 200 + k] * w[k * 200 + j];
            rel_out[i * 200 + j] = acc;
        }
    }
}

// ---- BN apply: read bf16 h from A's rows, write f32 out once ----
__global__ __launch_bounds__(256) void bn_apply(
    const unsigned short* __restrict__ hB, const float* __restrict__ scale,
    const float* __restrict__ shift, float* __restrict__ out) {
    __shared__ float ssc[200], ssh[200];
    if (threadIdx.x < 200) { ssc[threadIdx.x] = scale[threadIdx.x]; ssh[threadIdx.x] = shift[threadIdx.x]; }
    __syncthreads();
    const int total = N_NODES * 25;   // groups of 8 columns
    int stride = gridDim.x * blockDim.x;
    for (int i = blockIdx.x * blockDim.x + threadIdx.x; i < total; i += stride) {
        int v = i / 25;
        int g = i - v * 25;
        int c = g * 8;
        const unsigned short* hp = hB + (size_t)v * KTOT + c;
        ushort4 h0 = *reinterpret_cast<const ushort4*>(hp);
        ushort4 h1 = *reinterpret_cast<const ushort4*>(hp + 4);
        float4 o0, o1;
        o0.x = bf2f(h0.x) * ssc[c + 0] + ssh[c + 0];
        o0.y = bf2f(h0.y) * ssc[c + 1] + ssh[c + 1];
        o0.z = bf2f(h0.z) * ssc[c + 2] + ssh[c + 2];
        o0.w = bf2f(h0.w) * ssc[c + 3] + ssh[c + 3];
        o1.x = bf2f(h1.x) * ssc[c + 4] + ssh[c + 4];
        o1.y = bf2f(h1.y) * ssc[c + 5] + ssh[c + 5];
        o1.z = bf2f(h1.z) * ssc[c + 6] + ssh[c + 6];
        o1.w = bf2f(h1.w) * ssc[c + 7] + ssh[c + 7];
        float* op = out + (size_t)v * 200 + c;
        *reinterpret_cast<float4*>(op)     = o0;
        *reinterpret_cast<float4*>(op + 4) = o1;
    }
}

extern "C" void kernel_launch(void* const* d_in, const int* in_sizes, int n_in,
                              void* d_out, int out_size, void* d_ws, size_t ws_size,
                              hipStream_t stream) {
    const float* x         = (const float*)d_in[0];
    const float* rel_repr  = (const float*)d_in[1];
    const float* edge_norm = (const float*)d_in[2];
    const float* in_w      = (const float*)d_in[3];
    const float* out_w     = (const float*)d_in[4];
    const float* loop_w    = (const float*)d_in[5];
    const float* loop_rel  = (const float*)d_in[6];
    const float* w_rel     = (const float*)d_in[7];
    const float* bn_gamma  = (const float*)d_in[8];
    const float* bn_beta   = (const float*)d_in[9];
    const int* edge_src    = (const int*)d_in[10];
    const int* edge_dst    = (const int*)d_in[11];
    const int* edge_type   = (const int*)d_in[12];

    float* out = (float*)d_out;
    char* ws = (char*)d_ws;
    unsigned short* A  = (unsigned short*)(ws + A_OFF);
    unsigned short* Wt = (unsigned short*)(ws + WT_OFF);
    unsigned* hist     = (unsigned*)(ws + HIST_OFF);
    unsigned* cursor   = (unsigned*)(ws + CURSOR_OFF);
    float* scale       = (float*)(ws + SCALE_OFF);
    float* shift       = (float*)(ws + SHIFT_OFF);
    unsigned* rowptr   = (unsigned*)(ws + ROWPTR_OFF);
    unsigned* bsum     = (unsigned*)(ws + BSUM_OFF);
    int4* recs         = (int4*)(ws + REC_OFF);
    float* PS          = (float*)(ws + PS_OFF);
    float* PQ          = (float*)(ws + PQ_OFF);

    hipMemsetAsync(ws + ZERO_BASE, 0, ZERO_BYTES, stream);  // hist+cursor
    prep_k<<<PREP_NBLK, 256, 0, stream>>>(x, in_w, out_w, loop_w, loop_rel,
                                          edge_dst, A, Wt, hist);
    scan_part<<<SCAN_NBLK, 1024, 0, stream>>>(hist, bsum);
    scan_low<<<SCAN_NBLK, 1024, 0, stream>>>(hist, bsum, rowptr);
    fill_k<<<1563, 256, 0, stream>>>(edge_dst, edge_src, edge_type, edge_norm,
                                     rowptr, cursor, recs);
    aggregate<<<25000, 256, 0, stream>>>(rel_repr, rowptr, recs, A);
    gemm_nodes<<<GEMM_NBLK, 256, 0, stream>>>(A, Wt, PS, PQ);
    bnred_rel<<<400, 256, 0, stream>>>(PS, PQ, bn_gamma, bn_beta, rel_repr, w_rel,
                                       scale, shift, out + 20000000);
    bn_apply<<<1024, 256, 0, stream>>>(A, scale, shift, out);
}

// Round 9
// 335.012 us; speedup vs baseline: 1.5657x; 1.0281x over previous
//
#include <hip/hip_runtime.h>

#define N_NODES 100000
#define N_EDGES 400000
#define HALF_E  200000
#define BN_EPS  1e-5f

// A_bf layout per node row: [in 200 | out 200 | x 200 | pad 40] = 640 bf16 (1280 B)
// Within each 32-bf16 (64 B) chunk, 16B slot s of row v is stored at physical
// slot s ^ ((v>>1)&3)  -> linear global_load_lds staging + XOR'd ds_read_b128
// gives conflict-free (2-way) LDS reads in the GEMM (rule 21).
// AFTER the gemm k-loop, each tile-block overwrites slots [0,200) of its OWN
// rows with bf16 h (rows are tile-exclusive at that point) -> bn_apply reads
// 40 MB bf16 instead of 80 MB f32, and gemm writes 40 MB instead of 80 MB.
// CSR rows are DIRECTION-SORTED: in-edges fill from the front (atomicAdd on
// cursIn=rowptr[v]), out-edges from the back (atomicSub on cursOut=rowptr[v+1])
// -> aggregate's accumulator select becomes a wave-uniform scalar compare.
#define KTOT   640
#define CHUNKS 20
#define GEMM_NBLK 782

// LDS tile per buffer: A [0, 8192) = 128 rows x 64 B, W [8192, 24576) = 16 rows x 1024 B
// (W rows 13-15 staged with in-bounds garbage for uniform 6 loads/wave; never read)
#define LDS_BUF_BYTES 24576
#define LDS_W_OFF     8192

#define XSEG_NBLK 25000
#define PACK_NBLK 520
#define HIST_NBLK 1563
#define PREP_NBLK (XSEG_NBLK + PACK_NBLK + HIST_NBLK)

#define SCAN_NBLK 98                     // 98*1024 >= 100000

typedef __bf16 bf16x8 __attribute__((ext_vector_type(8)));
typedef float  f32x4  __attribute__((ext_vector_type(4)));

// ---- workspace layout (bytes) ----
#define A_OFF      0ull                  // 100000*640*2 = 128,000,000
#define WT_OFF     128000000ull          // 20*208*64 B = 266,240 (chunk-major, pre-swizzled)
#define HIST_OFF   128266240ull          // 100000*4  (repurposed as cursOut after scan_low)
#define CURSOR_OFF 128666240ull          // 100000*4  (cursIn, init by scan_low)
#define ZERO_BASE  HIST_OFF
#define ZERO_BYTES 400000ull             // hist only (cursors init'd by scan_low)
#define SCALE_OFF  129066240ull          // 200*4
#define SHIFT_OFF  129067040ull          // 200*4
#define ROWPTR_OFF 129069440ull          // 100001*4
#define BSUM_OFF   129469856ull          // 98*4
#define REC_OFF    129470640ull          // 400000*16 = 6,400,000 (16B aligned)
#define PS_OFF     135870640ull          // 782*200*4 = 625,600
#define PQ_OFF     136496240ull          // 782*200*4 -> end 137,121,840

static __device__ __forceinline__ unsigned short f2bf(float f) {
    union { float f; unsigned u; } v; v.f = f;
    unsigned u = v.u;
    unsigned r = (u + 0x7fffu + ((u >> 16) & 1u)) >> 16;  // RNE
    return (unsigned short)r;
}
static __device__ __forceinline__ float bf2f(unsigned short s) {
    union { unsigned u; float f; } v; v.u = ((unsigned)s) << 16; return v.f;
}

// physical bf16 offset of logical k within a row, given row swizzle s = (v>>1)&3
static __device__ __forceinline__ int swzk(int k, int s) {
    return (k & ~31) | (k & 7) | ((((k >> 3) & 3) ^ s) << 3);
}

// async global->LDS, 16 B per lane, linear LDS dest (wave-uniform base + lane*16)
static __device__ __forceinline__ void gload16(const void* g, void* l) {
    __builtin_amdgcn_global_load_lds(
        (const __attribute__((address_space(1))) void*)g,
        (__attribute__((address_space(3))) void*)l, 16, 0, 0);
}

// ---- fused prep: [0,25000) swizzled x-segment of A + zero pad;
// ---- [25000,25520) pack Wt; [25520,27083) dst-histogram (hist pre-zeroed) ----
__global__ __launch_bounds__(256) void prep_k(
    const float* __restrict__ x,
    const float* __restrict__ in_w, const float* __restrict__ out_w,
    const float* __restrict__ loop_w, const float* __restrict__ loop_rel,
    const int* __restrict__ edst,
    unsigned short* __restrict__ A, unsigned short* __restrict__ Wt,
    unsigned* __restrict__ hist) {
    int b = blockIdx.x;
    if (b < XSEG_NBLK) {
        int v = b * 4 + (threadIdx.x >> 6);
        int lane = threadIdx.x & 63;
        int s = (v >> 1) & 3;
        unsigned short* ar = A + (size_t)v * KTOT;
        if (lane < 50) {
            float4 xv = *reinterpret_cast<const float4*>(x + v * 200 + lane * 4);
            ushort4 w = make_ushort4(f2bf(xv.x), f2bf(xv.y), f2bf(xv.z), f2bf(xv.w));
            *reinterpret_cast<ushort4*>(ar + swzk(400 + lane * 4, s)) = w;
        }
        if (lane < 10)
            *reinterpret_cast<ushort4*>(ar + swzk(600 + lane * 4, s)) = make_ushort4(0, 0, 0, 0);
    } else if (b < XSEG_NBLK + PACK_NBLK) {
        // Wt layout: [c 20][n 208][slot_phys 4][8 bf16]
        int idx = (b - XSEG_NBLK) * 256 + threadIdx.x;   // 520*256 == 20*208*32
        int e = idx & 7;
        int t = idx >> 3;
        int sp = t & 3;
        int t2 = t >> 2;
        int n = t2 % 208;
        int c = t2 / 208;
        int sl = sp ^ ((n >> 1) & 3);
        int k = c * 32 + sl * 8 + e;
        float v = 0.f;
        if (n < 200) {
            if (k < 200)       v = in_w[k * 200 + n];
            else if (k < 400)  v = out_w[(k - 200) * 200 + n];
            else if (k < 600)  v = loop_w[(k - 400) * 200 + n] * loop_rel[k - 400];
        }
        Wt[idx] = f2bf(v);
    } else {
        int e = (b - XSEG_NBLK - PACK_NBLK) * 256 + threadIdx.x;
        if (e < N_EDGES) atomicAdd(&hist[edst[e]], 1u);
    }
}

// ---- scan pass 1: per-block sums ----
__global__ __launch_bounds__(1024) void scan_part(const unsigned* __restrict__ hist,
                                                  unsigned* __restrict__ bsum) {
    __shared__ unsigned s[1024];
    int idx = blockIdx.x * 1024 + threadIdx.x;
    s[threadIdx.x] = (idx < N_NODES) ? hist[idx] : 0u;
    __syncthreads();
    for (int off = 512; off > 0; off >>= 1) {
        if (threadIdx.x < off) s[threadIdx.x] += s[threadIdx.x + off];
        __syncthreads();
    }
    if (threadIdx.x == 0) bsum[blockIdx.x] = s[0];
}

// ---- scan pass 2 (merged top+low): intra-block exclusive scan + own block
// ---- offset from bsum; writes rowptr + cursIn (=beg) and repurposes hist
// ---- as cursOut (=end). Each thread touches only its own hist slot after
// ---- its last read of it. ----
__global__ __launch_bounds__(1024) void scan_low(unsigned* __restrict__ hist,
                                                 const unsigned* __restrict__ bsum,
                                                 unsigned* __restrict__ rowptr,
                                                 unsigned* __restrict__ cursIn) {
    __shared__ unsigned s[1024];
    __shared__ unsigned bs[128];
    int bid = blockIdx.x;
    if (threadIdx.x < 128)
        bs[threadIdx.x] = (threadIdx.x < SCAN_NBLK) ? bsum[threadIdx.x] : 0u;
    int idx = bid * 1024 + threadIdx.x;
    unsigned own = (idx < N_NODES) ? hist[idx] : 0u;
    s[threadIdx.x] = own;
    __syncthreads();
    unsigned boff = 0;
    for (int j = 0; j < bid; ++j) boff += bs[j];   // uniform loop
    for (int off = 1; off < 1024; off <<= 1) {
        unsigned t = 0;
        if ((int)threadIdx.x >= off) t = s[threadIdx.x - off];
        __syncthreads();
        if ((int)threadIdx.x >= off) s[threadIdx.x] += t;
        __syncthreads();
    }
    if (idx < N_NODES) {
        unsigned beg = boff + s[threadIdx.x] - own;
        rowptr[idx] = beg;
        cursIn[idx] = beg;           // in-edges fill from the front
        hist[idx]   = beg + own;     // cursOut: out-edges fill from the back
    }
    if (bid == 0 && threadIdx.x == 0) rowptr[N_NODES] = N_EDGES;
}

// ---- CSR fill, direction-sorted: in-edges (e<HALF) from front, out from back ----
__global__ __launch_bounds__(256) void fill_k(
    const int* __restrict__ edst, const int* __restrict__ esrc,
    const int* __restrict__ etyp, const float* __restrict__ norm,
    unsigned* __restrict__ cursIn, unsigned* __restrict__ cursOut,
    int4* __restrict__ recs) {
    int e = blockIdx.x * 256 + threadIdx.x;
    if (e < N_EDGES) {
        int d = edst[e];
        unsigned pos;
        if (e < HALF_E) pos = atomicAdd(&cursIn[d], 1u);
        else            pos = atomicSub(&cursOut[d], 1u) - 1u;
        recs[pos] = make_int4(esrc[e], etyp[e], __float_as_int(norm[e]), 0);
    }
}

// ---- gather aggregation: one wave per dst node; swizzled bf16 x-rows ----
// Direction-sorted rows: [beg,mid) in-edges -> aI, [mid,end) -> aO, where
// mid = cursIn[v] post-fill. Accumulator select is a wave-uniform scalar
// compare (beg/mid/end hoisted to SGPR) -> no per-lane cndmasks. 4 edges in
// flight per iteration (8 outstanding VMEM) to cover gather latency.
__global__ __launch_bounds__(256) void aggregate(
    const float* __restrict__ rel, const unsigned* __restrict__ rowptr,
    const unsigned* __restrict__ cursIn, const int4* __restrict__ recs,
    unsigned short* __restrict__ A) {
    int v = blockIdx.x * 4 + (threadIdx.x >> 6);
    int lane = threadIdx.x & 63;
    bool act = lane < 50;                    // lane owns dims [lane*4, lane*4+4)
    int col = lane * 4;
    int kx = 400 + col;                      // logical x position
    int kxb = (kx & ~31) | (kx & 7);         // swizzle-invariant part
    int kxs = (kx >> 3) & 3;                 // logical slot
    float4 aI = make_float4(0.f, 0.f, 0.f, 0.f);
    float4 aO = make_float4(0.f, 0.f, 0.f, 0.f);

    const unsigned short* __restrict__ Ab = A;
    auto xload = [&](int src) -> ushort4 {
        int s = (src >> 1) & 3;
        return *reinterpret_cast<const ushort4*>(
            Ab + (size_t)src * KTOT + kxb + ((kxs ^ s) << 3));
    };
    auto accI = [&](const int4& r, const ushort4& xv, const float4& rl) {
        float nz = __int_as_float(r.z);
        aI.x = fmaf(bf2f(xv.x) * rl.x, nz, aI.x);
        aI.y = fmaf(bf2f(xv.y) * rl.y, nz, aI.y);
        aI.z = fmaf(bf2f(xv.z) * rl.z, nz, aI.z);
        aI.w = fmaf(bf2f(xv.w) * rl.w, nz, aI.w);
    };
    auto accO = [&](const int4& r, const ushort4& xv, const float4& rl) {
        float nz = __int_as_float(r.z);
        aO.x = fmaf(bf2f(xv.x) * rl.x, nz, aO.x);
        aO.y = fmaf(bf2f(xv.y) * rl.y, nz, aO.y);
        aO.z = fmaf(bf2f(xv.z) * rl.z, nz, aO.z);
        aO.w = fmaf(bf2f(xv.w) * rl.w, nz, aO.w);
    };

    int beg = __builtin_amdgcn_readfirstlane(rowptr[v]);
    int end = __builtin_amdgcn_readfirstlane(rowptr[v + 1]);
    int mid = __builtin_amdgcn_readfirstlane(cursIn[v]);   // beg + nIn (post-fill)
    int j = beg;
    for (; j + 3 < end; j += 4) {
        int4 r0 = recs[j];
        int4 r1 = recs[j + 1];
        int4 r2 = recs[j + 2];
        int4 r3 = recs[j + 3];
        if (act) {
            ushort4 x0 = xload(r0.x);
            ushort4 x1 = xload(r1.x);
            ushort4 x2 = xload(r2.x);
            ushort4 x3 = xload(r3.x);
            float4 rl0 = *reinterpret_cast<const float4*>(rel + r0.y * 200 + col);
            float4 rl1 = *reinterpret_cast<const float4*>(rel + r1.y * 200 + col);
            float4 rl2 = *reinterpret_cast<const float4*>(rel + r2.y * 200 + col);
            float4 rl3 = *reinterpret_cast<const float4*>(rel + r3.y * 200 + col);
            if (j + 0 < mid) accI(r0, x0, rl0); else accO(r0, x0, rl0);
            if (j + 1 < mid) accI(r1, x1, rl1); else accO(r1, x1, rl1);
            if (j + 2 < mid) accI(r2, x2, rl2); else accO(r2, x2, rl2);
            if (j + 3 < mid) accI(r3, x3, rl3); else accO(r3, x3, rl3);
        }
    }
    if (j + 1 < end) {
        int4 r0 = recs[j];
        int4 r1 = recs[j + 1];
        if (act) {
            ushort4 x0 = xload(r0.x);
            ushort4 x1 = xload(r1.x);
            float4 rl0 = *reinterpret_cast<const float4*>(rel + r0.y * 200 + col);
            float4 rl1 = *reinterpret_cast<const float4*>(rel + r1.y * 200 + col);
            if (j + 0 < mid) accI(r0, x0, rl0); else accO(r0, x0, rl0);
            if (j + 1 < mid) accI(r1, x1, rl1); else accO(r1, x1, rl1);
        }
        j += 2;
    }
    if (j < end) {
        int4 r0 = recs[j];
        if (act) {
            ushort4 x0 = xload(r0.x);
            float4 rl0 = *reinterpret_cast<const float4*>(rel + r0.y * 200 + col);
            if (j < mid) accI(r0, x0, rl0); else accO(r0, x0, rl0);
        }
    }
    if (act) {
        int sv = (v >> 1) & 3;
        unsigned short* ar = A + (size_t)v * KTOT;
        ushort4 wI = make_ushort4(f2bf(aI.x), f2bf(aI.y), f2bf(aI.z), f2bf(aI.w));
        ushort4 wO = make_ushort4(f2bf(aO.x), f2bf(aO.y), f2bf(aO.z), f2bf(aO.w));
        *reinterpret_cast<ushort4*>(ar + swzk(col, sv))       = wI;
        *reinterpret_cast<ushort4*>(ar + swzk(200 + col, sv)) = wO;
    }
}

// ---- GEMM: h[v][n] = A_bf[v][:] . Wt[n][:] / 3 ; per-block BN partials ----
// Counted-vmcnt pipeline. Epilogue stores h as bf16 IN-PLACE into A's own
// rows (tile-exclusive after the k-loop).
__global__ __launch_bounds__(256) void gemm_nodes(
    unsigned short* __restrict__ A, const unsigned short* __restrict__ Wt,
    float* __restrict__ PS, float* __restrict__ PQ) {
    __shared__ __align__(16) char lds[2][LDS_BUF_BYTES];
    int tid = threadIdx.x;
    int wave = tid >> 6, lane = tid & 63;
    int quad = lane >> 4, l15 = lane & 15;
    int row0 = blockIdx.x * 128;
    int pslot16 = ((quad ^ ((l15 >> 1) & 3)) << 4);   // physical 16B slot for reads

    int sv0 = row0 + (wave * 2 + 0) * 16 + (lane >> 2);
    int sv1 = row0 + (wave * 2 + 1) * 16 + (lane >> 2);
    if (sv0 >= N_NODES) sv0 = N_NODES - 1;   // clamp; excluded from stats below
    if (sv1 >= N_NODES) sv1 = N_NODES - 1;
    const char* Ab = (const char*)A;
    const char* srcA0 = Ab + (size_t)sv0 * 1280 + (lane & 3) * 16;
    const char* srcA1 = Ab + (size_t)sv1 * 1280 + (lane & 3) * 16;
    const char* Wb = (const char*)Wt + lane * 16;

    int rdA0 = ((wave * 2 + 0) * 16 + l15) * 64 + pslot16;
    int rdA1 = ((wave * 2 + 1) * 16 + l15) * 64 + pslot16;
    int rdB  = LDS_W_OFF + l15 * 64 + pslot16;

    f32x4 acc[2][13];
#pragma unroll
    for (int i = 0; i < 2; ++i)
#pragma unroll
        for (int j = 0; j < 13; ++j) {
            acc[i][j].x = 0.f; acc[i][j].y = 0.f; acc[i][j].z = 0.f; acc[i][j].w = 0.f;
        }

    // stage chunk c into buffer lb: exactly 6 loads per wave
    auto stage = [&](int c, char* lb) {
        gload16(srcA0 + c * 64, lb + (wave * 2 + 0) * 1024);
        gload16(srcA1 + c * 64, lb + (wave * 2 + 1) * 1024);
        const char* wsrc = Wb + (size_t)c * 13312;
#pragma unroll
        for (int i = 0; i < 4; ++i) {
            int r = wave + i * 4;                 // LDS W row 0..15
            int srcr = (r < 13) ? r : (r - 13);   // in-bounds garbage for 13..15
            gload16(wsrc + srcr * 1024, lb + LDS_W_OFF + r * 1024);
        }
    };

    stage(0, lds[0]);
    stage(1, lds[1]);

#pragma unroll
    for (int c = 0; c < CHUNKS; ++c) {
        char* lb = lds[c & 1];
        if (c < CHUNKS - 1) {
            asm volatile("s_waitcnt vmcnt(6)" ::: "memory");   // chunk c's 6 done
        } else {
            asm volatile("s_waitcnt vmcnt(0)" ::: "memory");
        }
        __builtin_amdgcn_sched_barrier(0);
        __builtin_amdgcn_s_barrier();       // all waves' chunk-c data in LDS
        __builtin_amdgcn_sched_barrier(0);
        bf16x8 a0 = *reinterpret_cast<const bf16x8*>(lb + rdA0);
        bf16x8 a1 = *reinterpret_cast<const bf16x8*>(lb + rdA1);
#pragma unroll
        for (int nt = 0; nt < 13; ++nt) {
            bf16x8 b = *reinterpret_cast<const bf16x8*>(lb + rdB + nt * 1024);
            acc[0][nt] = __builtin_amdgcn_mfma_f32_16x16x32_bf16(a0, b, acc[0][nt], 0, 0, 0);
            acc[1][nt] = __builtin_amdgcn_mfma_f32_16x16x32_bf16(a1, b, acc[1][nt], 0, 0, 0);
        }
        __builtin_amdgcn_s_barrier();       // all waves done reading lb
        __builtin_amdgcn_sched_barrier(0);
        if (c + 2 < CHUNKS) stage(c + 2, lb);
    }

    // epilogue: store h bf16 in-place; per-wave column stats -> per-block partials
    float* redS = reinterpret_cast<float*>(lds[0]);        // [4][200]
    float* redQ = reinterpret_cast<float*>(lds[0]) + 800;  // [4][200]
#pragma unroll
    for (int nt = 0; nt < 13; ++nt) {
        int n = nt * 16 + l15;
        float s = 0.f, q = 0.f;
#pragma unroll
        for (int i = 0; i < 2; ++i) {
            int mbase = row0 + (wave * 2 + i) * 16 + quad * 4;
#pragma unroll
            for (int r = 0; r < 4; ++r) {
                float val = acc[i][nt][r] * (1.f / 3.f);
                int m = mbase + r;
                if (m < N_NODES) {
                    if (n < 200) A[(size_t)m * KTOT + n] = f2bf(val);
                    s += val; q += val * val;
                }
            }
        }
        s += __shfl_xor(s, 16); s += __shfl_xor(s, 32);
        q += __shfl_xor(q, 16); q += __shfl_xor(q, 32);
        if (lane < 16 && n < 200) {
            redS[wave * 200 + n] = s;
            redQ[wave * 200 + n] = q;
        }
    }
    __syncthreads();
    if (tid < 200) {
        float s = redS[tid] + redS[200 + tid] + redS[400 + tid] + redS[600 + tid];
        float q = redQ[tid] + redQ[200 + tid] + redQ[400 + tid] + redQ[600 + tid];
        PS[blockIdx.x * 200 + tid] = s;
        PQ[blockIdx.x * 200 + tid] = q;
    }
}

// ---- fused: blocks [0,200) BN-reduce per column; blocks [200,400) rel_out rows ----
__global__ __launch_bounds__(256) void bnred_rel(
    const float* __restrict__ PS, const float* __restrict__ PQ,
    const float* __restrict__ gamma, const float* __restrict__ beta,
    const float* __restrict__ rel, const float* __restrict__ w,
    float* __restrict__ scale, float* __restrict__ shift,
    float* __restrict__ rel_out) {
    if (blockIdx.x < 200) {
        __shared__ float ls[256], lq[256];
        int c = blockIdx.x;
        float s = 0.f, q = 0.f;
        for (int b = threadIdx.x; b < GEMM_NBLK; b += 256) {
            s += PS[b * 200 + c];
            q += PQ[b * 200 + c];
        }
        ls[threadIdx.x] = s; lq[threadIdx.x] = q;
        __syncthreads();
        for (int off = 128; off > 0; off >>= 1) {
            if (threadIdx.x < off) {
                ls[threadIdx.x] += ls[threadIdx.x + off];
                lq[threadIdx.x] += lq[threadIdx.x + off];
            }
            __syncthreads();
        }
        if (threadIdx.x == 0) {
            float mean = ls[0] * (1.f / N_NODES);
            float var = lq[0] * (1.f / N_NODES) - mean * mean;
            float inv = rsqrtf(var + BN_EPS);
            float sc = inv * gamma[c];
            scale[c] = sc;
            shift[c] = beta[c] - mean * sc;
        }
    } else {
        int i = blockIdx.x - 200, j = threadIdx.x;
        if (j < 200) {
            float acc = 0.f;
            for (int k = 0; k < 200; ++k) acc += rel[i * 200 + k] * w[k * 200 + j];
            rel_out[i * 200 + j] = acc;
        }
    }
}

// ---- BN apply: read bf16 h from A's rows, write f32 out once ----
__global__ __launch_bounds__(256) void bn_apply(
    const unsigned short* __restrict__ hB, const float* __restrict__ scale,
    const float* __restrict__ shift, float* __restrict__ out) {
    __shared__ float ssc[200], ssh[200];
    if (threadIdx.x < 200) { ssc[threadIdx.x] = scale[threadIdx.x]; ssh[threadIdx.x] = shift[threadIdx.x]; }
    __syncthreads();
    const int total = N_NODES * 25;   // groups of 8 columns
    int stride = gridDim.x * blockDim.x;
    for (int i = blockIdx.x * blockDim.x + threadIdx.x; i < total; i += stride) {
        int v = i / 25;
        int g = i - v * 25;
        int c = g * 8;
        const unsigned short* hp = hB + (size_t)v * KTOT + c;
        ushort4 h0 = *reinterpret_cast<const ushort4*>(hp);
        ushort4 h1 = *reinterpret_cast<const ushort4*>(hp + 4);
        float4 o0, o1;
        o0.x = bf2f(h0.x) * ssc[c + 0] + ssh[c + 0];
        o0.y = bf2f(h0.y) * ssc[c + 1] + ssh[c + 1];
        o0.z = bf2f(h0.z) * ssc[c + 2] + ssh[c + 2];
        o0.w = bf2f(h0.w) * ssc[c + 3] + ssh[c + 3];
        o1.x = bf2f(h1.x) * ssc[c + 4] + ssh[c + 4];
        o1.y = bf2f(h1.y) * ssc[c + 5] + ssh[c + 5];
        o1.z = bf2f(h1.z) * ssc[c + 6] + ssh[c + 6];
        o1.w = bf2f(h1.w) * ssc[c + 7] + ssh[c + 7];
        float* op = out + (size_t)v * 200 + c;
        *reinterpret_cast<float4*>(op)     = o0;
        *reinterpret_cast<float4*>(op + 4) = o1;
    }
}

extern "C" void kernel_launch(void* const* d_in, const int* in_sizes, int n_in,
                              void* d_out, int out_size, void* d_ws, size_t ws_size,
                              hipStream_t stream) {
    const float* x         = (const float*)d_in[0];
    const float* rel_repr  = (const float*)d_in[1];
    const float* edge_norm = (const float*)d_in[2];
    const float* in_w      = (const float*)d_in[3];
    const float* out_w     = (const float*)d_in[4];
    const float* loop_w    = (const float*)d_in[5];
    const float* loop_rel  = (const float*)d_in[6];
    const float* w_rel     = (const float*)d_in[7];
    const float* bn_gamma  = (const float*)d_in[8];
    const float* bn_beta   = (const float*)d_in[9];
    const int* edge_src    = (const int*)d_in[10];
    const int* edge_dst    = (const int*)d_in[11];
    const int* edge_type   = (const int*)d_in[12];

    float* out = (float*)d_out;
    char* ws = (char*)d_ws;
    unsigned short* A  = (unsigned short*)(ws + A_OFF);
    unsigned short* Wt = (unsigned short*)(ws + WT_OFF);
    unsigned* hist     = (unsigned*)(ws + HIST_OFF);    // becomes cursOut
    unsigned* cursIn   = (unsigned*)(ws + CURSOR_OFF);
    float* scale       = (float*)(ws + SCALE_OFF);
    float* shift       = (float*)(ws + SHIFT_OFF);
    unsigned* rowptr   = (unsigned*)(ws + ROWPTR_OFF);
    unsigned* bsum     = (unsigned*)(ws + BSUM_OFF);
    int4* recs         = (int4*)(ws + REC_OFF);
    float* PS          = (float*)(ws + PS_OFF);
    float* PQ          = (float*)(ws + PQ_OFF);

    hipMemsetAsync(ws + ZERO_BASE, 0, ZERO_BYTES, stream);  // hist only
    prep_k<<<PREP_NBLK, 256, 0, stream>>>(x, in_w, out_w, loop_w, loop_rel,
                                          edge_dst, A, Wt, hist);
    scan_part<<<SCAN_NBLK, 1024, 0, stream>>>(hist, bsum);
    scan_low<<<SCAN_NBLK, 1024, 0, stream>>>(hist, bsum, rowptr, cursIn);
    fill_k<<<1563, 256, 0, stream>>>(edge_dst, edge_src, edge_type, edge_norm,
                                     cursIn, hist, recs);
    aggregate<<<25000, 256, 0, stream>>>(rel_repr, rowptr, cursIn, recs, A);
    gemm_nodes<<<GEMM_NBLK, 256, 0, stream>>>(A, Wt, PS, PQ);
    bnred_rel<<<400, 256, 0, stream>>>(PS, PQ, bn_gamma, bn_beta, rel_repr, w_rel,
                                       scale, shift, out + 20000000);
    bn_apply<<<1024, 256, 0, stream>>>(A, scale, shift, out);
}